// Round 1
// baseline (1559.039 us; speedup 1.0000x reference)
//
#include <hip/hip_runtime.h>
#include <math.h>

// Problem constants
#define NB   2
#define CCH  128
#define HS   48          // x2 spatial
#define LL   2304        // 48*48 patches / spatial locations
#define KP   1152        // 128*3*3 patch size (x2)
#define KW   2048        // 128*4*4 patch size (x1)
#define HO   96          // output spatial

// Workspace layout (floats). P/T/W are per-batch (reused batch 0 then 1).
#define P_OFF   0
#define T_OFF   (LL*KP)                          // 2,654,208
#define W_OFF   (T_OFF + LL*LL)                  // 7,962,624
#define Y_OFF   (W_OFF + (size_t)LL*KW)          // 12,681,216
#define NRM_OFF (Y_OFF + (size_t)NB*CCH*HO*HO)   // 15,040,512
#define MM_OFF  (NRM_OFF + NB*LL)                // 15,045,120
// total = 15,049,728 floats = 60.2 MB

// ---------------------------------------------------------------------------
// Build P[p][k] = x2 3x3 patch im2col (zero padded). p=(i,j), k=(c,di,dj).
__global__ __launch_bounds__(256) void build_P_k(const float* __restrict__ x2,
                                                 float* __restrict__ P, int n) {
    int idx = blockIdx.x * 256 + threadIdx.x;          // < LL*KP exactly
    int k = idx % KP;
    int p = idx / KP;
    int c = k / 9;
    int t = k - c * 9;
    int di = t / 3, dj = t - di * 3;
    int i = p / HS, j = p - (p / HS) * HS;
    int ii = i + di - 1, jj = j + dj - 1;
    float v = 0.0f;
    if (ii >= 0 && ii < HS && jj >= 0 && jj < HS)
        v = x2[((n * CCH + c) * HS + ii) * HS + jj];
    P[idx] = v;
}

// ---------------------------------------------------------------------------
// Per-patch L2 norm of P rows + "mask fully zero in 3x3 neighborhood" flag.
__global__ __launch_bounds__(256) void norms_mm_k(const float* __restrict__ P,
                                                  const float* __restrict__ mask,
                                                  float* __restrict__ norms,
                                                  float* __restrict__ mmb, int n) {
    int wid  = (blockIdx.x * 256 + threadIdx.x) >> 6;  // global wave id = patch l
    int lane = threadIdx.x & 63;
    if (wid >= LL) return;
    const float* row = P + (size_t)wid * KP;
    float s = 0.0f;
    for (int k = lane; k < KP; k += 64) { float x = row[k]; s += x * x; }
    #pragma unroll
    for (int o = 32; o; o >>= 1) s += __shfl_down(s, o);
    if (lane == 0) {
        norms[n * LL + wid] = sqrtf(s);
        int i = wid / HS, j = wid - (wid / HS) * HS;
        float msum = 0.0f;
        for (int di = -1; di <= 1; di++)
            for (int dj = -1; dj <= 1; dj++) {
                int ii = i + di, jj = j + dj;
                if (ii >= 0 && ii < HS && jj >= 0 && jj < HS)
                    msum += mask[(n * HS + ii) * HS + jj];
            }
        mmb[n * LL + wid] = (msum == 0.0f) ? 1.0f : 0.0f;
    }
}

// ---------------------------------------------------------------------------
// T[p][l] = (P[p] . P[l]) / max(norm[l], 1e-4).  M=N=2304, K=1152.
__global__ __launch_bounds__(256) void gemm1_k(const float* __restrict__ P,
                                               const float* __restrict__ norms,
                                               float* __restrict__ T, int n) {
    __shared__ __align__(16) float As[16][68];
    __shared__ __align__(16) float Bs[16][68];
    int tid = threadIdx.x;
    int tx = tid & 15, ty = tid >> 4;
    int m0 = blockIdx.x * 64, n0 = blockIdx.y * 64;
    float acc[4][4] = {{0.f}};
    int lrow = tid >> 2;            // 0..63
    int lk4  = (tid & 3) * 4;       // 0,4,8,12
    const float* Arow = P + (size_t)(m0 + lrow) * KP + lk4;
    const float* Brow = P + (size_t)(n0 + lrow) * KP + lk4;

    for (int k0 = 0; k0 < KP; k0 += 16) {
        float4 av = *(const float4*)(Arow + k0);
        float4 bv = *(const float4*)(Brow + k0);
        As[lk4 + 0][lrow] = av.x; As[lk4 + 1][lrow] = av.y;
        As[lk4 + 2][lrow] = av.z; As[lk4 + 3][lrow] = av.w;
        Bs[lk4 + 0][lrow] = bv.x; Bs[lk4 + 1][lrow] = bv.y;
        Bs[lk4 + 2][lrow] = bv.z; Bs[lk4 + 3][lrow] = bv.w;
        __syncthreads();
        #pragma unroll
        for (int kk = 0; kk < 16; kk++) {
            float ar[4], br[4];
            *(float4*)ar = *(const float4*)&As[kk][ty * 4];
            *(float4*)br = *(const float4*)&Bs[kk][tx * 4];
            #pragma unroll
            for (int i = 0; i < 4; i++)
                #pragma unroll
                for (int j = 0; j < 4; j++)
                    acc[i][j] += ar[i] * br[j];
        }
        __syncthreads();
    }

    float rn[4];
    #pragma unroll
    for (int j = 0; j < 4; j++)
        rn[j] = 1.0f / fmaxf(norms[n * LL + n0 + tx * 4 + j], 1e-4f);
    #pragma unroll
    for (int i = 0; i < 4; i++) {
        int p = m0 + ty * 4 + i;
        float4 o;
        o.x = acc[i][0] * rn[0]; o.y = acc[i][1] * rn[1];
        o.z = acc[i][2] * rn[2]; o.w = acc[i][3] * rn[3];
        *(float4*)&T[(size_t)p * LL + n0 + tx * 4] = o;
    }
}

// ---------------------------------------------------------------------------
// Row-wise masked softmax over l (row length 2304) + neighbor boost, in place.
__global__ __launch_bounds__(256) void softmax_k(float* __restrict__ T,
                                                 const float* __restrict__ mmb,
                                                 const float* __restrict__ mask_all,
                                                 int n) {
    int p = blockIdx.x;
    int tid = threadIdx.x;
    __shared__ float red[8];
    float* row = T + (size_t)p * LL;
    float ma = mask_all[n * LL + p];
    float v[9];
    float mx = -3.0e38f;
    #pragma unroll
    for (int e = 0; e < 9; e++) {
        int l = tid + e * 256;
        float s = row[l] * mmb[n * LL + l] * ma * 10.0f;
        v[e] = s;
        mx = fmaxf(mx, s);
    }
    #pragma unroll
    for (int o = 32; o; o >>= 1) mx = fmaxf(mx, __shfl_down(mx, o));
    int wid = tid >> 6, lane = tid & 63;
    if (lane == 0) red[wid] = mx;
    __syncthreads();
    mx = fmaxf(fmaxf(red[0], red[1]), fmaxf(red[2], red[3]));
    float sum = 0.0f;
    #pragma unroll
    for (int e = 0; e < 9; e++) { v[e] = __expf(v[e] - mx); sum += v[e]; }
    #pragma unroll
    for (int o = 32; o; o >>= 1) sum += __shfl_down(sum, o);
    if (lane == 0) red[4 + wid] = sum;
    __syncthreads();
    sum = red[4] + red[5] + red[6] + red[7];
    float inv = 1.0f / sum;
    int pi = p / HS, pj = p - (p / HS) * HS;
    #pragma unroll
    for (int e = 0; e < 9; e++) {
        int l = tid + e * 256;
        int li = l / HS, lj = l - (l / HS) * HS;
        bool nb = (li == pi && (lj == pj - 1 || lj == pj + 1)) ||
                  (lj == pj && (li == pi - 1 || li == pi + 1));
        float z = v[e] * inv * (nb ? 1.5f : 1.0f) * mmb[n * LL + l] * ma;
        row[l] = fmaxf(z, 1e-8f);
    }
}

// ---------------------------------------------------------------------------
// Build W[l][f] = x1 4x4 stride-2 patch im2col. l=(li,lj), f=(c,ky,kx).
__global__ __launch_bounds__(256) void build_W_k(const float* __restrict__ x1,
                                                 float* __restrict__ Wm, int n) {
    int idx = blockIdx.x * 256 + threadIdx.x;          // < LL*KW exactly
    int f = idx & (KW - 1);
    int l = idx >> 11;
    int c = f >> 4, ky = (f >> 2) & 3, kx = f & 3;
    int li = l / HS, lj = l - (l / HS) * HS;
    int yy = 2 * li - 1 + ky, xx = 2 * lj - 1 + kx;
    float v = 0.0f;
    if (yy >= 0 && yy < HO && xx >= 0 && xx < HO)
        v = x1[((n * CCH + c) * HO + yy) * HO + xx];
    Wm[idx] = v;
}

// ---------------------------------------------------------------------------
// V[p][f] = sum_l T[p][l] * W[l][f]; epilogue: overlap-add 0.25*V into ybuf.
// M=2304, N=2048, K=2304.
__global__ __launch_bounds__(256) void gemm2_k(const float* __restrict__ T,
                                               const float* __restrict__ Wm,
                                               float* __restrict__ ybuf, int n) {
    __shared__ __align__(16) float As[16][68];
    __shared__ __align__(16) float Bs[16][68];
    int tid = threadIdx.x;
    int tx = tid & 15, ty = tid >> 4;
    int m0 = blockIdx.x * 64, n0 = blockIdx.y * 64;
    float acc[4][4] = {{0.f}};
    int lrow = tid >> 2;
    int lk4  = (tid & 3) * 4;
    const float* Arow = T + (size_t)(m0 + lrow) * LL + lk4;
    int krow = tid >> 4;            // 0..15
    int nq   = (tid & 15) * 4;
    const float* Bptr = Wm + (size_t)krow * KW + n0 + nq;

    for (int k0 = 0; k0 < LL; k0 += 16) {
        float4 av = *(const float4*)(Arow + k0);
        As[lk4 + 0][lrow] = av.x; As[lk4 + 1][lrow] = av.y;
        As[lk4 + 2][lrow] = av.z; As[lk4 + 3][lrow] = av.w;
        float4 bv = *(const float4*)(Bptr + (size_t)k0 * KW);
        *(float4*)&Bs[krow][nq] = bv;
        __syncthreads();
        #pragma unroll
        for (int kk = 0; kk < 16; kk++) {
            float ar[4], br[4];
            *(float4*)ar = *(const float4*)&As[kk][ty * 4];
            *(float4*)br = *(const float4*)&Bs[kk][tx * 4];
            #pragma unroll
            for (int i = 0; i < 4; i++)
                #pragma unroll
                for (int j = 0; j < 4; j++)
                    acc[i][j] += ar[i] * br[j];
        }
        __syncthreads();
    }

    #pragma unroll
    for (int i = 0; i < 4; i++) {
        int p = m0 + ty * 4 + i;
        int pi = p / HS, pj = p - (p / HS) * HS;
        #pragma unroll
        for (int j = 0; j < 4; j++) {
            int f = n0 + tx * 4 + j;
            int c = f >> 4, ky = (f >> 2) & 3, kx = f & 3;
            int yy = 2 * pi - 1 + ky, xx = 2 * pj - 1 + kx;
            if (yy >= 0 && yy < HO && xx >= 0 && xx < HO)
                atomicAdd(&ybuf[((size_t)(n * CCH + c) * HO + yy) * HO + xx],
                          0.25f * acc[i][j]);
        }
    }
}

// ---------------------------------------------------------------------------
// Four dilated 3x3 convs (d = 1<<g), 128 -> 16 channels each, bias + relu.
__global__ __launch_bounds__(256) void fuse_k(const float* __restrict__ ybuf,
                                              const float* __restrict__ fw,
                                              const float* __restrict__ fb,
                                              float* __restrict__ out) {
    int n = blockIdx.z, g = blockIdx.y;
    int tile = blockIdx.x;
    int ty0 = (tile / 6) * 16, tx0 = (tile - (tile / 6) * 6) * 16;
    const int d = 1 << g;
    int tid = threadIdx.x;
    int tx = tid & 15, ty = tid >> 4;
    __shared__ float lt[4][33 * 32];
    float acc[16];
    #pragma unroll
    for (int oc = 0; oc < 16; oc++) acc[oc] = 0.0f;

    for (int c0 = 0; c0 < CCH; c0 += 4) {
        __syncthreads();
        for (int i = tid; i < 4 * 1024; i += 256) {
            int cc = i >> 10;
            int rr = (i >> 5) & 31;
            int col = i & 31;
            int gy = ty0 - d + rr, gx = tx0 - d + col;
            float v = 0.0f;
            if (gy >= 0 && gy < HO && gx >= 0 && gx < HO)
                v = ybuf[((size_t)(n * CCH + c0 + cc) * HO + gy) * HO + gx];
            lt[cc][rr * 33 + col] = v;
        }
        __syncthreads();
        #pragma unroll
        for (int cc = 0; cc < 4; cc++) {
            int c = c0 + cc;
            float yv[9];
            #pragma unroll
            for (int t = 0; t < 9; t++)
                yv[t] = lt[cc][(ty + d * (t / 3)) * 33 + tx + d * (t % 3)];
            const float* wp = fw + ((size_t)g * 16 * CCH + c) * 9;
            #pragma unroll
            for (int oc = 0; oc < 16; oc++) {
                #pragma unroll
                for (int t = 0; t < 9; t++)
                    acc[oc] += yv[t] * wp[(size_t)oc * CCH * 9 + t];
            }
        }
    }

    int gy = ty0 + ty, gx = tx0 + tx;
    #pragma unroll
    for (int oc = 0; oc < 16; oc++) {
        float r = fmaxf(acc[oc] + fb[g * 16 + oc], 0.0f);
        out[((size_t)(n * 64 + g * 16 + oc) * HO + gy) * HO + gx] = r;
    }
}

// ---------------------------------------------------------------------------
extern "C" void kernel_launch(void* const* d_in, const int* in_sizes, int n_in,
                              void* d_out, int out_size, void* d_ws, size_t ws_size,
                              hipStream_t stream) {
    const float* x1       = (const float*)d_in[0];
    const float* x2       = (const float*)d_in[1];
    const float* mask     = (const float*)d_in[2];
    const float* mask_all = (const float*)d_in[3];
    const float* fw       = (const float*)d_in[4];
    const float* fb       = (const float*)d_in[5];
    float* out = (float*)d_out;
    float* ws  = (float*)d_ws;

    float* P     = ws + P_OFF;
    float* T     = ws + T_OFF;
    float* Wm    = ws + W_OFF;
    float* yb    = ws + Y_OFF;
    float* norms = ws + NRM_OFF;
    float* mmb   = ws + MM_OFF;

    hipMemsetAsync(yb, 0, (size_t)NB * CCH * HO * HO * sizeof(float), stream);

    for (int n = 0; n < NB; n++) {
        build_P_k<<<(LL * KP) / 256, 256, 0, stream>>>(x2, P, n);
        norms_mm_k<<<LL / 4, 256, 0, stream>>>(P, mask, norms, mmb, n);
        gemm1_k<<<dim3(36, 36), 256, 0, stream>>>(P, norms, T, n);
        softmax_k<<<LL, 256, 0, stream>>>(T, mmb, mask_all, n);
        build_W_k<<<(LL * KW) / 256, 256, 0, stream>>>(x1, Wm, n);
        gemm2_k<<<dim3(36, 32), 256, 0, stream>>>(T, Wm, yb, n);
    }
    fuse_k<<<dim3(36, 4, 2), 256, 0, stream>>>(yb, fw, fb, out);
}

// Round 2
// 488.844 us; speedup vs baseline: 3.1892x; 3.1892x over previous
//
#include <hip/hip_runtime.h>
#include <math.h>

typedef unsigned short u16;
typedef unsigned int   u32;
typedef float f32x4 __attribute__((ext_vector_type(4)));
typedef short bfx8  __attribute__((ext_vector_type(8)));

#define NB   2
#define CCH  128
#define HS   48
#define LL   2304        // 48*48
#define KP   1152        // 128*3*3
#define KW   2048        // 128*4*4
#define HO   96
#define TB_LD 4608       // Tb (bf16 attention) row stride in u16 elements

// Workspace byte offsets (total ~50.8 MB; round-1 used 60.2 MB successfully)
#define PHI_B 0                  // P hi  bf16: 2304*1152*2 = 5,308,416
#define PLO_B 5308416            // P lo  bf16: 5,308,416
#define WT_B  10616832           // W^T   bf16: 2048*2304*2 = 9,437,184
#define T_B   20054016           // T fp32: 2304*2304*4 = 21,233,664 (bf16 Tb aliased, stride 4608)
#define YB_B  41287680           // y fp32: 2*128*96*96*4 = 9,437,184
#define NRM_B 50724864           // norms: 2*2304*4
#define MM_B  50743296           // mm flags: 2*2304*4

__device__ __forceinline__ u16 f2bf(float f) {      // round-to-nearest-even
    u32 u = __float_as_uint(f);
    u32 r = (u + 0x7fffu + ((u >> 16) & 1u)) >> 16;
    return (u16)r;
}
__device__ __forceinline__ float bf2f(u16 h) {
    return __uint_as_float(((u32)h) << 16);
}
// async global->LDS, 16B per lane; LDS dest = wave-uniform base + lane*16
__device__ __forceinline__ void gll16(const void* g, void* l) {
    __builtin_amdgcn_global_load_lds((const __attribute__((address_space(1))) void*)g,
                                     (__attribute__((address_space(3))) void*)l, 16, 0, 0);
}

// ---------------------------------------------------------------------------
// P (x2 3x3 im2col) as bf16 hi/lo split.
__global__ __launch_bounds__(256) void build_P_k(const float* __restrict__ x2,
                                                 u16* __restrict__ Ph, u16* __restrict__ Pl, int n) {
    int idx = blockIdx.x * 256 + threadIdx.x;     // exactly LL*KP
    int k = idx % KP, p = idx / KP;
    int c = k / 9, t = k - c * 9;
    int di = t / 3, dj = t - di * 3;
    int i = p / HS, j = p - (p / HS) * HS;
    int ii = i + di - 1, jj = j + dj - 1;
    float v = 0.0f;
    if (ii >= 0 && ii < HS && jj >= 0 && jj < HS)
        v = x2[((n * CCH + c) * HS + ii) * HS + jj];
    u16 h = f2bf(v);
    Ph[idx] = h;
    Pl[idx] = f2bf(v - bf2f(h));
}

// ---------------------------------------------------------------------------
// fp32 patch norms (from x2 directly) + mask-zero-neighborhood flag.
__global__ __launch_bounds__(256) void norms_mm_k(const float* __restrict__ x2,
                                                  const float* __restrict__ mask,
                                                  float* __restrict__ norms,
                                                  float* __restrict__ mmb, int n) {
    int wid  = (blockIdx.x * 256 + threadIdx.x) >> 6;
    int lane = threadIdx.x & 63;
    if (wid >= LL) return;
    int i = wid / HS, j = wid - (wid / HS) * HS;
    float s = 0.0f;
    for (int k = lane; k < KP; k += 64) {
        int c = k / 9, t = k - (k / 9) * 9;
        int di = t / 3, dj = t - di * 3;
        int ii = i + di - 1, jj = j + dj - 1;
        if (ii >= 0 && ii < HS && jj >= 0 && jj < HS) {
            float x = x2[((n * CCH + c) * HS + ii) * HS + jj];
            s += x * x;
        }
    }
    #pragma unroll
    for (int o = 32; o; o >>= 1) s += __shfl_down(s, o);
    if (lane == 0) {
        norms[n * LL + wid] = sqrtf(s);
        float msum = 0.0f;
        for (int di = -1; di <= 1; di++)
            for (int dj = -1; dj <= 1; dj++) {
                int ii = i + di, jj = j + dj;
                if (ii >= 0 && ii < HS && jj >= 0 && jj < HS)
                    msum += mask[(n * HS + ii) * HS + jj];
            }
        mmb[n * LL + wid] = (msum == 0.0f) ? 1.0f : 0.0f;
    }
}

// ---------------------------------------------------------------------------
// T[p][l] = (P[p].P[l]) / max(norm[l],1e-4), split-bf16 MFMA (hi*hi+hi*lo+lo*hi).
// NT gemm: both operands are rows of P. 128x128 tile, 4 waves, 16x16x32 bf16.
__global__ __launch_bounds__(256) void gemm1_k(const u16* __restrict__ Ph, const u16* __restrict__ Pl,
                                               const float* __restrict__ norms,
                                               float* __restrict__ T, int n) {
    __shared__ __align__(16) u16 Ah[4096], Al[4096], Bh[4096], Bl[4096];
    int tid = threadIdx.x, w = tid >> 6, lane = tid & 63;
    int m0 = blockIdx.x * 128, n0 = blockIdx.y * 128;
    size_t aoff = (size_t)(m0 + (tid >> 2)) * KP + (tid & 3) * 8;
    size_t boff = (size_t)(n0 + (tid >> 2)) * KP + (tid & 3) * 8;
    int wm = (w >> 1) * 64, wn = (w & 1) * 64;
    int fr = lane & 15, fq = (lane >> 4) * 8;
    f32x4 acc[4][4];
    #pragma unroll
    for (int i = 0; i < 4; i++)
        #pragma unroll
        for (int j = 0; j < 4; j++) acc[i][j] = (f32x4)0.0f;

    for (int k0 = 0; k0 < KP; k0 += 32) {
        if (k0) __syncthreads();
        gll16(Ph + aoff + k0,           Ah + w * 512);
        gll16(Ph + aoff + 64 * KP + k0, Ah + 2048 + w * 512);
        gll16(Pl + aoff + k0,           Al + w * 512);
        gll16(Pl + aoff + 64 * KP + k0, Al + 2048 + w * 512);
        gll16(Ph + boff + k0,           Bh + w * 512);
        gll16(Ph + boff + 64 * KP + k0, Bh + 2048 + w * 512);
        gll16(Pl + boff + k0,           Bl + w * 512);
        gll16(Pl + boff + 64 * KP + k0, Bl + 2048 + w * 512);
        __syncthreads();
        bfx8 ah[4], al[4], bh[4], bl[4];
        #pragma unroll
        for (int i = 0; i < 4; i++) {
            int r = wm + i * 16 + fr;
            ah[i] = *(const bfx8*)&Ah[r * 32 + fq];
            al[i] = *(const bfx8*)&Al[r * 32 + fq];
        }
        #pragma unroll
        for (int j = 0; j < 4; j++) {
            int r = wn + j * 16 + fr;
            bh[j] = *(const bfx8*)&Bh[r * 32 + fq];
            bl[j] = *(const bfx8*)&Bl[r * 32 + fq];
        }
        #pragma unroll
        for (int i = 0; i < 4; i++)
            #pragma unroll
            for (int j = 0; j < 4; j++) {
                acc[i][j] = __builtin_amdgcn_mfma_f32_16x16x32_bf16(ah[i], bh[j], acc[i][j], 0, 0, 0);
                acc[i][j] = __builtin_amdgcn_mfma_f32_16x16x32_bf16(ah[i], bl[j], acc[i][j], 0, 0, 0);
                acc[i][j] = __builtin_amdgcn_mfma_f32_16x16x32_bf16(al[i], bh[j], acc[i][j], 0, 0, 0);
            }
    }
    // epilogue: C/D layout col=lane&15, row=(lane>>4)*4+reg
    #pragma unroll
    for (int j = 0; j < 4; j++) {
        int col = n0 + wn + j * 16 + fr;
        float rn = 1.0f / fmaxf(norms[n * LL + col], 1e-4f);
        #pragma unroll
        for (int i = 0; i < 4; i++) {
            int rbase = m0 + wm + i * 16 + (lane >> 4) * 4;
            #pragma unroll
            for (int r = 0; r < 4; r++)
                T[(size_t)(rbase + r) * LL + col] = acc[i][j][r] * rn;
        }
    }
}

// ---------------------------------------------------------------------------
// Row softmax (fp32 in) -> bf16 attention weights Tb (stride 4608, aliased
// over T's storage; each block reads its whole row before writing).
__global__ __launch_bounds__(256) void softmax_k(const float* __restrict__ T,
                                                 u16* __restrict__ Tb,
                                                 const float* __restrict__ mmb,
                                                 const float* __restrict__ mask_all, int n) {
    int p = blockIdx.x, tid = threadIdx.x;
    __shared__ float red[8];
    const float* row = T + (size_t)p * LL;
    u16* orow = Tb + (size_t)p * TB_LD;
    float ma = mask_all[n * LL + p];
    float v[9], mmr[9];
    float mx = -3.0e38f;
    #pragma unroll
    for (int e = 0; e < 9; e++) {
        int l = tid + e * 256;
        float m_ = mmb[n * LL + l];
        mmr[e] = m_;
        float s = row[l] * m_ * ma * 10.0f;
        v[e] = s;
        mx = fmaxf(mx, s);
    }
    #pragma unroll
    for (int o = 32; o; o >>= 1) mx = fmaxf(mx, __shfl_down(mx, o));
    int wid = tid >> 6, lane = tid & 63;
    if (lane == 0) red[wid] = mx;
    __syncthreads();
    mx = fmaxf(fmaxf(red[0], red[1]), fmaxf(red[2], red[3]));
    float sum = 0.0f;
    #pragma unroll
    for (int e = 0; e < 9; e++) { v[e] = __expf(v[e] - mx); sum += v[e]; }
    #pragma unroll
    for (int o = 32; o; o >>= 1) sum += __shfl_down(sum, o);
    if (lane == 0) red[4 + wid] = sum;
    __syncthreads();
    float inv = 1.0f / (red[4] + red[5] + red[6] + red[7]);
    int pi = p / HS, pj = p - (p / HS) * HS;
    #pragma unroll
    for (int e = 0; e < 9; e++) {
        int l = tid + e * 256;
        int li = l / HS, lj = l - (l / HS) * HS;
        bool nb = (li == pi && (lj == pj - 1 || lj == pj + 1)) ||
                  (lj == pj && (li == pi - 1 || li == pi + 1));
        float z = v[e] * inv * (nb ? 1.5f : 1.0f) * mmr[e] * ma;
        orow[l] = f2bf(fmaxf(z, 1e-8f));
    }
}

// ---------------------------------------------------------------------------
// W^T[f][l] bf16 (x1 4x4 stride-2 im2col, transposed for NT gemm).
__global__ __launch_bounds__(256) void build_W_k(const float* __restrict__ x1,
                                                 u16* __restrict__ Wt, int n) {
    int idx = blockIdx.x * 256 + threadIdx.x;     // exactly KW*LL
    int l = idx % LL, f = idx / LL;
    int c = f >> 4, ky = (f >> 2) & 3, kx = f & 3;
    int li = l / HS, lj = l - (l / HS) * HS;
    int yy = 2 * li - 1 + ky, xx = 2 * lj - 1 + kx;
    float v = 0.0f;
    if (yy >= 0 && yy < HO && xx >= 0 && xx < HO)
        v = x1[((n * CCH + c) * HO + yy) * HO + xx];
    Wt[idx] = f2bf(v);
}

// ---------------------------------------------------------------------------
// V[p][f] = sum_l Tb[p][l]*Wt[f][l] (bf16 MFMA); epilogue overlap-add 0.25*V.
__global__ __launch_bounds__(256) void gemm2_k(const u16* __restrict__ Tb, const u16* __restrict__ Wt,
                                               float* __restrict__ yb, int n) {
    __shared__ __align__(16) u16 As[4096], Bs[4096];
    int tid = threadIdx.x, w = tid >> 6, lane = tid & 63;
    int m0 = blockIdx.x * 128, n0 = blockIdx.y * 128;
    size_t aoff = (size_t)(m0 + (tid >> 2)) * TB_LD + (tid & 3) * 8;
    size_t boff = (size_t)(n0 + (tid >> 2)) * LL + (tid & 3) * 8;
    int wm = (w >> 1) * 64, wn = (w & 1) * 64;
    int fr = lane & 15, fq = (lane >> 4) * 8;
    f32x4 acc[4][4];
    #pragma unroll
    for (int i = 0; i < 4; i++)
        #pragma unroll
        for (int j = 0; j < 4; j++) acc[i][j] = (f32x4)0.0f;

    for (int k0 = 0; k0 < LL; k0 += 32) {
        if (k0) __syncthreads();
        gll16(Tb + aoff + k0,             As + w * 512);
        gll16(Tb + aoff + 64 * TB_LD + k0, As + 2048 + w * 512);
        gll16(Wt + boff + k0,             Bs + w * 512);
        gll16(Wt + boff + 64 * LL + k0,   Bs + 2048 + w * 512);
        __syncthreads();
        bfx8 af[4], bf[4];
        #pragma unroll
        for (int i = 0; i < 4; i++) af[i] = *(const bfx8*)&As[(wm + i * 16 + fr) * 32 + fq];
        #pragma unroll
        for (int j = 0; j < 4; j++) bf[j] = *(const bfx8*)&Bs[(wn + j * 16 + fr) * 32 + fq];
        #pragma unroll
        for (int i = 0; i < 4; i++)
            #pragma unroll
            for (int j = 0; j < 4; j++)
                acc[i][j] = __builtin_amdgcn_mfma_f32_16x16x32_bf16(af[i], bf[j], acc[i][j], 0, 0, 0);
    }
    #pragma unroll
    for (int j = 0; j < 4; j++) {
        int f = n0 + wn + j * 16 + fr;
        int c = f >> 4, ky = (f >> 2) & 3, kx = f & 3;
        #pragma unroll
        for (int i = 0; i < 4; i++) {
            int rbase = m0 + wm + i * 16 + (lane >> 4) * 4;
            #pragma unroll
            for (int r = 0; r < 4; r++) {
                int p = rbase + r;
                int pi = p / HS, pj = p - (p / HS) * HS;
                int yy = 2 * pi - 1 + ky, xx = 2 * pj - 1 + kx;
                if (yy >= 0 && yy < HO && xx >= 0 && xx < HO)
                    atomicAdd(&yb[((size_t)(n * CCH + c) * HO + yy) * HO + xx],
                              0.25f * acc[i][j][r]);
            }
        }
    }
}

// ---------------------------------------------------------------------------
// Dilated 3x3 convs, channel-split x4 for occupancy; partial sums -> out (atomics).
__global__ __launch_bounds__(256) void fuse_k(const float* __restrict__ ybuf,
                                              const float* __restrict__ fw,
                                              float* __restrict__ out) {
    int n = blockIdx.z;
    int g = blockIdx.y >> 2, cs = blockIdx.y & 3;
    int tile = blockIdx.x;
    int ty0 = (tile / 6) * 16, tx0 = (tile - (tile / 6) * 6) * 16;
    const int d = 1 << g;
    int tid = threadIdx.x;
    int tx = tid & 15, ty = tid >> 4;
    __shared__ float lt[4][33 * 32];
    float acc[16];
    #pragma unroll
    for (int oc = 0; oc < 16; oc++) acc[oc] = 0.0f;

    for (int c0 = cs * 32; c0 < cs * 32 + 32; c0 += 4) {
        __syncthreads();
        for (int i = tid; i < 4 * 1024; i += 256) {
            int cc = i >> 10;
            int rr = (i >> 5) & 31;
            int col = i & 31;
            int gy = ty0 - d + rr, gx = tx0 - d + col;
            float v = 0.0f;
            if (gy >= 0 && gy < HO && gx >= 0 && gx < HO)
                v = ybuf[((size_t)(n * CCH + c0 + cc) * HO + gy) * HO + gx];
            lt[cc][rr * 33 + col] = v;
        }
        __syncthreads();
        #pragma unroll
        for (int cc = 0; cc < 4; cc++) {
            int c = c0 + cc;
            float yv[9];
            #pragma unroll
            for (int t = 0; t < 9; t++)
                yv[t] = lt[cc][(ty + d * (t / 3)) * 33 + tx + d * (t % 3)];
            const float* wp = fw + ((size_t)g * 16 * CCH + c) * 9;
            #pragma unroll
            for (int oc = 0; oc < 16; oc++) {
                #pragma unroll
                for (int t = 0; t < 9; t++)
                    acc[oc] += yv[t] * wp[(size_t)oc * CCH * 9 + t];
            }
        }
    }
    int gy = ty0 + ty, gx = tx0 + tx;
    #pragma unroll
    for (int oc = 0; oc < 16; oc++)
        atomicAdd(&out[((size_t)(n * 64 + g * 16 + oc) * HO + gy) * HO + gx], acc[oc]);
}

__global__ __launch_bounds__(256) void bias_relu_k(float* __restrict__ out,
                                                   const float* __restrict__ fb) {
    int idx = blockIdx.x * 256 + threadIdx.x;     // exactly 2*64*96*96
    int ch = (idx / (HO * HO)) & 63;
    out[idx] = fmaxf(out[idx] + fb[ch], 0.0f);
}

// ---------------------------------------------------------------------------
extern "C" void kernel_launch(void* const* d_in, const int* in_sizes, int n_in,
                              void* d_out, int out_size, void* d_ws, size_t ws_size,
                              hipStream_t stream) {
    const float* x1       = (const float*)d_in[0];
    const float* x2       = (const float*)d_in[1];
    const float* mask     = (const float*)d_in[2];
    const float* mask_all = (const float*)d_in[3];
    const float* fw       = (const float*)d_in[4];
    const float* fb       = (const float*)d_in[5];
    float* out = (float*)d_out;
    char* wsb  = (char*)d_ws;

    u16*   Phi   = (u16*)(wsb + PHI_B);
    u16*   Plo   = (u16*)(wsb + PLO_B);
    u16*   Wt    = (u16*)(wsb + WT_B);
    float* T     = (float*)(wsb + T_B);
    u16*   Tb    = (u16*)(wsb + T_B);      // aliased, stride 4608 u16 per row
    float* yb    = (float*)(wsb + YB_B);
    float* norms = (float*)(wsb + NRM_B);
    float* mmb   = (float*)(wsb + MM_B);

    hipMemsetAsync(yb, 0, (size_t)NB * CCH * HO * HO * sizeof(float), stream);
    hipMemsetAsync(out, 0, (size_t)out_size * sizeof(float), stream);

    for (int n = 0; n < NB; n++) {
        build_P_k<<<(LL * KP) / 256, 256, 0, stream>>>(x2, Phi, Plo, n);
        norms_mm_k<<<LL / 4, 256, 0, stream>>>(x2, mask, norms, mmb, n);
        gemm1_k<<<dim3(18, 18), 256, 0, stream>>>(Phi, Plo, norms, T, n);
        softmax_k<<<LL, 256, 0, stream>>>(T, Tb, mmb, mask_all, n);
        build_W_k<<<(KW * LL) / 256, 256, 0, stream>>>(x1, Wt, n);
        gemm2_k<<<dim3(18, 16), 256, 0, stream>>>(Tb, Wt, yb, n);
    }
    fuse_k<<<dim3(36, 16, 2), 256, 0, stream>>>(yb, fw, out);
    bias_relu_k<<<(NB * 64 * HO * HO) / 256, 256, 0, stream>>>(out, fb);
}

// Round 3
// 430.965 us; speedup vs baseline: 3.6176x; 1.1343x over previous
//
#include <hip/hip_runtime.h>
#include <math.h>

typedef unsigned short u16;
typedef unsigned int   u32;
typedef float f32x4 __attribute__((ext_vector_type(4)));
typedef short bfx8  __attribute__((ext_vector_type(8)));

#define NB   2
#define CCH  128
#define HS   48
#define LL   2304        // 48*48
#define KP   1152        // 128*3*3
#define KW   2048        // 128*4*4
#define HO   96
#define PIX  9216        // 96*96
#define TB_LD 4608       // Tb (bf16 attention) row stride in u16 elements

// Workspace byte offsets (total ~55.6 MB; 60.2 MB known-safe from round 0)
#define PHI_B 0                  // P hi  bf16: 2304*1152*2 = 5,308,416
#define PLO_B 5308416            // P lo  bf16
#define WT_B  10616832           // W^T   bf16: 2048*2304*2 = 9,437,184
#define T_B   20054016           // T fp32: 2304*2304*4 = 21,233,664 (bf16 Tb aliased)
#define YB_B  41287680           // y fp32: 2*128*96*96*4 = 9,437,184
#define NRM_B 50724864           // norms: 2*2304*4
#define MM_B  50743296           // mm flags: 2*2304*4
#define YT_B  50761728           // yT bf16 [2][9216][128] = 4,718,592
#define WF_B  55480320           // fuse weights bf16 [64][9][128] = 147,456

__device__ __forceinline__ u16 f2bf(float f) {      // round-to-nearest-even
    u32 u = __float_as_uint(f);
    u32 r = (u + 0x7fffu + ((u >> 16) & 1u)) >> 16;
    return (u16)r;
}
__device__ __forceinline__ float bf2f(u16 h) {
    return __uint_as_float(((u32)h) << 16);
}
__device__ __forceinline__ void gll16(const void* g, void* l) {
    __builtin_amdgcn_global_load_lds((const __attribute__((address_space(1))) void*)g,
                                     (__attribute__((address_space(3))) void*)l, 16, 0, 0);
}

// ---------------------------------------------------------------------------
__global__ __launch_bounds__(256) void build_P_k(const float* __restrict__ x2,
                                                 u16* __restrict__ Ph, u16* __restrict__ Pl, int n) {
    int idx = blockIdx.x * 256 + threadIdx.x;
    int k = idx % KP, p = idx / KP;
    int c = k / 9, t = k - c * 9;
    int di = t / 3, dj = t - di * 3;
    int i = p / HS, j = p - (p / HS) * HS;
    int ii = i + di - 1, jj = j + dj - 1;
    float v = 0.0f;
    if (ii >= 0 && ii < HS && jj >= 0 && jj < HS)
        v = x2[((n * CCH + c) * HS + ii) * HS + jj];
    u16 h = f2bf(v);
    Ph[idx] = h;
    Pl[idx] = f2bf(v - bf2f(h));
}

// ---------------------------------------------------------------------------
__global__ __launch_bounds__(256) void norms_mm_k(const float* __restrict__ x2,
                                                  const float* __restrict__ mask,
                                                  float* __restrict__ norms,
                                                  float* __restrict__ mmb, int n) {
    int wid  = (blockIdx.x * 256 + threadIdx.x) >> 6;
    int lane = threadIdx.x & 63;
    if (wid >= LL) return;
    int i = wid / HS, j = wid - (wid / HS) * HS;
    float s = 0.0f;
    for (int k = lane; k < KP; k += 64) {
        int c = k / 9, t = k - (k / 9) * 9;
        int di = t / 3, dj = t - di * 3;
        int ii = i + di - 1, jj = j + dj - 1;
        if (ii >= 0 && ii < HS && jj >= 0 && jj < HS) {
            float x = x2[((n * CCH + c) * HS + ii) * HS + jj];
            s += x * x;
        }
    }
    #pragma unroll
    for (int o = 32; o; o >>= 1) s += __shfl_down(s, o);
    if (lane == 0) {
        norms[n * LL + wid] = sqrtf(s);
        float msum = 0.0f;
        for (int di = -1; di <= 1; di++)
            for (int dj = -1; dj <= 1; dj++) {
                int ii = i + di, jj = j + dj;
                if (ii >= 0 && ii < HS && jj >= 0 && jj < HS)
                    msum += mask[(n * HS + ii) * HS + jj];
            }
        mmb[n * LL + wid] = (msum == 0.0f) ? 1.0f : 0.0f;
    }
}

// ---------------------------------------------------------------------------
// T[p][l] = (P[p].P[l]) / max(norm[l],1e-4), split-bf16 MFMA.
__global__ __launch_bounds__(256) void gemm1_k(const u16* __restrict__ Ph, const u16* __restrict__ Pl,
                                               const float* __restrict__ norms,
                                               float* __restrict__ T, int n) {
    __shared__ __align__(16) u16 Ah[4096], Al[4096], Bh[4096], Bl[4096];
    int tid = threadIdx.x, w = tid >> 6, lane = tid & 63;
    int m0 = blockIdx.x * 128, n0 = blockIdx.y * 128;
    size_t aoff = (size_t)(m0 + (tid >> 2)) * KP + (tid & 3) * 8;
    size_t boff = (size_t)(n0 + (tid >> 2)) * KP + (tid & 3) * 8;
    int wm = (w >> 1) * 64, wn = (w & 1) * 64;
    int fr = lane & 15, fq = (lane >> 4) * 8;
    f32x4 acc[4][4];
    #pragma unroll
    for (int i = 0; i < 4; i++)
        #pragma unroll
        for (int j = 0; j < 4; j++) acc[i][j] = (f32x4)0.0f;

    for (int k0 = 0; k0 < KP; k0 += 32) {
        if (k0) __syncthreads();
        gll16(Ph + aoff + k0,           Ah + w * 512);
        gll16(Ph + aoff + 64 * KP + k0, Ah + 2048 + w * 512);
        gll16(Pl + aoff + k0,           Al + w * 512);
        gll16(Pl + aoff + 64 * KP + k0, Al + 2048 + w * 512);
        gll16(Ph + boff + k0,           Bh + w * 512);
        gll16(Ph + boff + 64 * KP + k0, Bh + 2048 + w * 512);
        gll16(Pl + boff + k0,           Bl + w * 512);
        gll16(Pl + boff + 64 * KP + k0, Bl + 2048 + w * 512);
        __syncthreads();
        bfx8 ah[4], al[4], bh[4], bl[4];
        #pragma unroll
        for (int i = 0; i < 4; i++) {
            int r = wm + i * 16 + fr;
            ah[i] = *(const bfx8*)&Ah[r * 32 + fq];
            al[i] = *(const bfx8*)&Al[r * 32 + fq];
        }
        #pragma unroll
        for (int j = 0; j < 4; j++) {
            int r = wn + j * 16 + fr;
            bh[j] = *(const bfx8*)&Bh[r * 32 + fq];
            bl[j] = *(const bfx8*)&Bl[r * 32 + fq];
        }
        #pragma unroll
        for (int i = 0; i < 4; i++)
            #pragma unroll
            for (int j = 0; j < 4; j++) {
                acc[i][j] = __builtin_amdgcn_mfma_f32_16x16x32_bf16(ah[i], bh[j], acc[i][j], 0, 0, 0);
                acc[i][j] = __builtin_amdgcn_mfma_f32_16x16x32_bf16(ah[i], bl[j], acc[i][j], 0, 0, 0);
                acc[i][j] = __builtin_amdgcn_mfma_f32_16x16x32_bf16(al[i], bh[j], acc[i][j], 0, 0, 0);
            }
    }
    #pragma unroll
    for (int j = 0; j < 4; j++) {
        int col = n0 + wn + j * 16 + fr;
        float rn = 1.0f / fmaxf(norms[n * LL + col], 1e-4f);
        #pragma unroll
        for (int i = 0; i < 4; i++) {
            int rbase = m0 + wm + i * 16 + (lane >> 4) * 4;
            #pragma unroll
            for (int r = 0; r < 4; r++)
                T[(size_t)(rbase + r) * LL + col] = acc[i][j][r] * rn;
        }
    }
}

// ---------------------------------------------------------------------------
__global__ __launch_bounds__(256) void softmax_k(const float* __restrict__ T,
                                                 u16* __restrict__ Tb,
                                                 const float* __restrict__ mmb,
                                                 const float* __restrict__ mask_all, int n) {
    int p = blockIdx.x, tid = threadIdx.x;
    __shared__ float red[8];
    const float* row = T + (size_t)p * LL;
    u16* orow = Tb + (size_t)p * TB_LD;
    float ma = mask_all[n * LL + p];
    float v[9], mmr[9];
    float mx = -3.0e38f;
    #pragma unroll
    for (int e = 0; e < 9; e++) {
        int l = tid + e * 256;
        float m_ = mmb[n * LL + l];
        mmr[e] = m_;
        float s = row[l] * m_ * ma * 10.0f;
        v[e] = s;
        mx = fmaxf(mx, s);
    }
    #pragma unroll
    for (int o = 32; o; o >>= 1) mx = fmaxf(mx, __shfl_down(mx, o));
    int wid = tid >> 6, lane = tid & 63;
    if (lane == 0) red[wid] = mx;
    __syncthreads();
    mx = fmaxf(fmaxf(red[0], red[1]), fmaxf(red[2], red[3]));
    float sum = 0.0f;
    #pragma unroll
    for (int e = 0; e < 9; e++) { v[e] = __expf(v[e] - mx); sum += v[e]; }
    #pragma unroll
    for (int o = 32; o; o >>= 1) sum += __shfl_down(sum, o);
    if (lane == 0) red[4 + wid] = sum;
    __syncthreads();
    float inv = 1.0f / (red[4] + red[5] + red[6] + red[7]);
    int pi = p / HS, pj = p - (p / HS) * HS;
    #pragma unroll
    for (int e = 0; e < 9; e++) {
        int l = tid + e * 256;
        int li = l / HS, lj = l - (l / HS) * HS;
        bool nb = (li == pi && (lj == pj - 1 || lj == pj + 1)) ||
                  (lj == pj && (li == pi - 1 || li == pi + 1));
        float z = v[e] * inv * (nb ? 1.5f : 1.0f) * mmr[e] * ma;
        orow[l] = f2bf(fmaxf(z, 1e-8f));
    }
}

// ---------------------------------------------------------------------------
__global__ __launch_bounds__(256) void build_W_k(const float* __restrict__ x1,
                                                 u16* __restrict__ Wt, int n) {
    int idx = blockIdx.x * 256 + threadIdx.x;
    int l = idx % LL, f = idx / LL;
    int c = f >> 4, ky = (f >> 2) & 3, kx = f & 3;
    int li = l / HS, lj = l - (l / HS) * HS;
    int yy = 2 * li - 1 + ky, xx = 2 * lj - 1 + kx;
    float v = 0.0f;
    if (yy >= 0 && yy < HO && xx >= 0 && xx < HO)
        v = x1[((n * CCH + c) * HO + yy) * HO + xx];
    Wt[idx] = f2bf(v);
}

// ---------------------------------------------------------------------------
__global__ __launch_bounds__(256) void gemm2_k(const u16* __restrict__ Tb, const u16* __restrict__ Wt,
                                               float* __restrict__ yb, int n) {
    __shared__ __align__(16) u16 As[4096], Bs[4096];
    int tid = threadIdx.x, w = tid >> 6, lane = tid & 63;
    int m0 = blockIdx.x * 128, n0 = blockIdx.y * 128;
    size_t aoff = (size_t)(m0 + (tid >> 2)) * TB_LD + (tid & 3) * 8;
    size_t boff = (size_t)(n0 + (tid >> 2)) * LL + (tid & 3) * 8;
    int wm = (w >> 1) * 64, wn = (w & 1) * 64;
    int fr = lane & 15, fq = (lane >> 4) * 8;
    f32x4 acc[4][4];
    #pragma unroll
    for (int i = 0; i < 4; i++)
        #pragma unroll
        for (int j = 0; j < 4; j++) acc[i][j] = (f32x4)0.0f;

    for (int k0 = 0; k0 < LL; k0 += 32) {
        if (k0) __syncthreads();
        gll16(Tb + aoff + k0,              As + w * 512);
        gll16(Tb + aoff + 64 * TB_LD + k0, As + 2048 + w * 512);
        gll16(Wt + boff + k0,              Bs + w * 512);
        gll16(Wt + boff + 64 * LL + k0,    Bs + 2048 + w * 512);
        __syncthreads();
        bfx8 af[4], bf[4];
        #pragma unroll
        for (int i = 0; i < 4; i++) af[i] = *(const bfx8*)&As[(wm + i * 16 + fr) * 32 + fq];
        #pragma unroll
        for (int j = 0; j < 4; j++) bf[j] = *(const bfx8*)&Bs[(wn + j * 16 + fr) * 32 + fq];
        #pragma unroll
        for (int i = 0; i < 4; i++)
            #pragma unroll
            for (int j = 0; j < 4; j++)
                acc[i][j] = __builtin_amdgcn_mfma_f32_16x16x32_bf16(af[i], bf[j], acc[i][j], 0, 0, 0);
    }
    #pragma unroll
    for (int j = 0; j < 4; j++) {
        int f = n0 + wn + j * 16 + fr;
        int c = f >> 4, ky = (f >> 2) & 3, kx = f & 3;
        #pragma unroll
        for (int i = 0; i < 4; i++) {
            int rbase = m0 + wm + i * 16 + (lane >> 4) * 4;
            #pragma unroll
            for (int r = 0; r < 4; r++) {
                int p = rbase + r;
                int pi = p / HS, pj = p - (p / HS) * HS;
                int yy = 2 * pi - 1 + ky, xx = 2 * pj - 1 + kx;
                if (yy >= 0 && yy < HO && xx >= 0 && xx < HO)
                    atomicAdd(&yb[((size_t)(n * CCH + c) * HO + yy) * HO + xx],
                              0.25f * acc[i][j][r]);
            }
        }
    }
}

// ---------------------------------------------------------------------------
// yb fp32 [n][c][96][96] -> yT bf16 [n][pix][128] via LDS transpose.
__global__ __launch_bounds__(256) void y2bf_k(const float* __restrict__ yb,
                                              u16* __restrict__ yT) {
    __shared__ float lt[32][130];
    int blk = blockIdx.x;                 // 576 blocks: 2*9216/32
    int n  = blk / (PIX / 32);
    int pq0 = (blk - n * (PIX / 32)) * 32;
    int tid = threadIdx.x;
    #pragma unroll
    for (int i = tid; i < 32 * 128; i += 256) {
        int c = i >> 5, p = i & 31;
        lt[p][c] = yb[((size_t)(n * CCH + c)) * PIX + pq0 + p];
    }
    __syncthreads();
    #pragma unroll
    for (int i = tid; i < 32 * 128; i += 256) {
        int p = i >> 7, c = i & 127;
        yT[((size_t)(n * PIX + pq0 + p)) * CCH + c] = f2bf(lt[p][c]);
    }
}

// fuse weights fp32 [g][oc][c][ky][kx] -> bf16 Wf[go=g*16+oc][tap][c]
__global__ __launch_bounds__(256) void wprep_k(const float* __restrict__ fw,
                                               u16* __restrict__ Wf) {
    int idx = blockIdx.x * 256 + threadIdx.x;      // 64*9*128 = 73728
    int c = idx & 127;
    int tap = (idx >> 7) % 9;
    int go = idx / (128 * 9);
    Wf[idx] = f2bf(fw[((size_t)go * 128 + c) * 9 + tap]);
}

// ---------------------------------------------------------------------------
// Fuse conv as implicit gemm: per wave one 16-pixel x 16-oc MFMA tile,
// K = 9 taps x 128 ch. A from yT (predicated 16B loads), B from Wf. No LDS.
__global__ __launch_bounds__(256) void fuse_mfma_k(const u16* __restrict__ yT,
                                                   const u16* __restrict__ Wf,
                                                   const float* __restrict__ fb,
                                                   float* __restrict__ out) {
    int n = blockIdx.z, g = blockIdx.y;
    const int d = 1 << g;
    int tid = threadIdx.x, wv = tid >> 6, lane = tid & 63;
    int pix0 = blockIdx.x * 64 + wv * 16;          // within-batch pixel base
    int h = pix0 / HO, w0 = pix0 - h * HO;         // 16 | 96 so row-aligned
    int m = lane & 15, q = lane >> 4;
    int oc = m;                                    // B row index = lane&15
    const u16* brow = Wf + ((size_t)(g * 16 + oc) * 9) * CCH + q * 8;
    f32x4 acc = (f32x4)0.0f;

    #pragma unroll
    for (int tap = 0; tap < 9; tap++) {
        int dy = (tap / 3 - 1) * d, dx = (tap % 3 - 1) * d;
        int hh = h + dy;
        int ww = w0 + m + dx;
        bool v = (hh >= 0) & (hh < HO) & (ww >= 0) & (ww < HO);
        const u16* arow = yT + ((size_t)(n * PIX + hh * HO + ww)) * CCH + q * 8;
        const u16* bt = brow + tap * CCH;
        #pragma unroll
        for (int c0 = 0; c0 < CCH; c0 += 32) {
            bfx8 af = (bfx8)0;
            if (v) af = *(const bfx8*)(arow + c0);
            bfx8 bf = *(const bfx8*)(bt + c0);
            acc = __builtin_amdgcn_mfma_f32_16x16x32_bf16(af, bf, acc, 0, 0, 0);
        }
    }
    // C/D: col(lane&15)=oc, row=(lane>>4)*4+r = pixel
    float bias = fb[g * 16 + oc];
    f32x4 o;
    #pragma unroll
    for (int r = 0; r < 4; r++) o[r] = fmaxf(acc[r] + bias, 0.0f);
    size_t oi = ((size_t)(n * 64 + g * 16 + oc)) * PIX + pix0 + q * 4;
    *(f32x4*)&out[oi] = o;
}

// ---------------------------------------------------------------------------
extern "C" void kernel_launch(void* const* d_in, const int* in_sizes, int n_in,
                              void* d_out, int out_size, void* d_ws, size_t ws_size,
                              hipStream_t stream) {
    const float* x1       = (const float*)d_in[0];
    const float* x2       = (const float*)d_in[1];
    const float* mask     = (const float*)d_in[2];
    const float* mask_all = (const float*)d_in[3];
    const float* fw       = (const float*)d_in[4];
    const float* fb       = (const float*)d_in[5];
    float* out = (float*)d_out;
    char* wsb  = (char*)d_ws;

    u16*   Phi   = (u16*)(wsb + PHI_B);
    u16*   Plo   = (u16*)(wsb + PLO_B);
    u16*   Wt    = (u16*)(wsb + WT_B);
    float* T     = (float*)(wsb + T_B);
    u16*   Tb    = (u16*)(wsb + T_B);
    float* yb    = (float*)(wsb + YB_B);
    float* norms = (float*)(wsb + NRM_B);
    float* mmb   = (float*)(wsb + MM_B);
    u16*   yT    = (u16*)(wsb + YT_B);
    u16*   Wf    = (u16*)(wsb + WF_B);

    hipMemsetAsync(yb, 0, (size_t)NB * CCH * HO * HO * sizeof(float), stream);
    wprep_k<<<(64 * 9 * 128) / 256, 256, 0, stream>>>(fw, Wf);

    for (int n = 0; n < NB; n++) {
        build_P_k<<<(LL * KP) / 256, 256, 0, stream>>>(x2, Phi, Plo, n);
        norms_mm_k<<<LL / 4, 256, 0, stream>>>(x2, mask, norms, mmb, n);
        gemm1_k<<<dim3(18, 18), 256, 0, stream>>>(Phi, Plo, norms, T, n);
        softmax_k<<<LL, 256, 0, stream>>>(T, Tb, mmb, mask_all, n);
        build_W_k<<<(KW * LL) / 256, 256, 0, stream>>>(x1, Wt, n);
        gemm2_k<<<dim3(18, 16), 256, 0, stream>>>(Tb, Wt, yb, n);
    }
    y2bf_k<<<NB * PIX / 32, 256, 0, stream>>>(yb, yT);
    fuse_mfma_k<<<dim3(PIX / 64, 4, NB), 256, 0, stream>>>(yT, Wf, fb, out);
}